// Round 1
// baseline (53.026 us; speedup 1.0000x reference)
//
#include <hip/hip_runtime.h>
#include <math.h>

// Problem constants (from reference setup_inputs)
#define SERIES   16384        // S: columns
#define BROWS    1941         // B: rows
#define NELEM    (BROWS * SERIES)        // 31,801,344
#define NELEM4   (NELEM / 4)             // 7,950,336 (S divisible by 4 -> rows stay aligned)
#define RBLOCKS  2048
#define RTHREADS 256

// Kernel 1: gather per-series start indexes into workspace.
__global__ __launch_bounds__(256) void gather_starts(
    const int* __restrict__ indexes,
    const int* __restrict__ rvsi,
    int* __restrict__ starts)
{
    int i = blockIdx.x * blockDim.x + threadIdx.x;
    if (i < SERIES) starts[i] = rvsi[indexes[i]];
}

// Kernel 2: masked squared-error partial reduction (deterministic, no atomics).
__global__ __launch_bounds__(RTHREADS) void masked_sq_reduce(
    const float4* __restrict__ p,
    const float4* __restrict__ a,
    const int4*  __restrict__ starts,   // [SERIES/4]
    float*        __restrict__ blockSum,
    unsigned int* __restrict__ blockCount)
{
    float sum = 0.0f;
    unsigned int cnt = 0;

    const int stride = gridDim.x * blockDim.x;
    for (int v = blockIdx.x * blockDim.x + threadIdx.x; v < NELEM4; v += stride) {
        float4 pv = p[v];
        float4 av = a[v];
        int e  = v << 2;              // flat element index, < 2^25, fits int
        int j  = e >> 14;             // row (time index)
        int i4 = (e & (SERIES - 1)) >> 2;  // column group
        int4 st = starts[i4];

        float d0 = pv.x - av.x;
        float d1 = pv.y - av.y;
        float d2 = pv.z - av.z;
        float d3 = pv.w - av.w;
        if (j >= st.x) { sum += d0 * d0; cnt++; }
        if (j >= st.y) { sum += d1 * d1; cnt++; }
        if (j >= st.z) { sum += d2 * d2; cnt++; }
        if (j >= st.w) { sum += d3 * d3; cnt++; }
    }

    __shared__ float        ssum[RTHREADS];
    __shared__ unsigned int scnt[RTHREADS];
    ssum[threadIdx.x] = sum;
    scnt[threadIdx.x] = cnt;
    __syncthreads();
    for (int off = RTHREADS / 2; off > 0; off >>= 1) {
        if (threadIdx.x < off) {
            ssum[threadIdx.x] += ssum[threadIdx.x + off];
            scnt[threadIdx.x] += scnt[threadIdx.x + off];
        }
        __syncthreads();
    }
    if (threadIdx.x == 0) {
        blockSum[blockIdx.x]   = ssum[0];
        blockCount[blockIdx.x] = scnt[0];
    }
}

// Kernel 3: final reduction of 2048 partials -> sqrt(sum/count).
__global__ __launch_bounds__(256) void finalize(
    const float* __restrict__ blockSum,
    const unsigned int* __restrict__ blockCount,
    float* __restrict__ out)
{
    __shared__ float        ssum[256];
    __shared__ unsigned int scnt[256];
    float s = 0.0f;
    unsigned int c = 0;
    for (int i = threadIdx.x; i < RBLOCKS; i += 256) {
        s += blockSum[i];
        c += blockCount[i];
    }
    ssum[threadIdx.x] = s;
    scnt[threadIdx.x] = c;
    __syncthreads();
    for (int off = 128; off > 0; off >>= 1) {
        if (threadIdx.x < off) {
            ssum[threadIdx.x] += ssum[threadIdx.x + off];
            scnt[threadIdx.x] += scnt[threadIdx.x + off];
        }
        __syncthreads();
    }
    if (threadIdx.x == 0) {
        out[0] = sqrtf(ssum[0] / (float)scnt[0]);
    }
}

extern "C" void kernel_launch(void* const* d_in, const int* in_sizes, int n_in,
                              void* d_out, int out_size, void* d_ws, size_t ws_size,
                              hipStream_t stream)
{
    const float* predictions = (const float*)d_in[0];   // [B, S]
    const float* actuals     = (const float*)d_in[1];   // [B, S]
    const int*   indexes     = (const int*)d_in[2];     // [S]
    const int*   rvsi        = (const int*)d_in[3];     // [N_SERIES]
    float* out = (float*)d_out;

    // Workspace layout (all 4-byte types; ws is at least 256-aligned):
    //   [0, 64KB)            : int starts[SERIES]
    //   [64KB, 64KB+8KB)     : float blockSum[RBLOCKS]
    //   [72KB, 72KB+8KB)     : uint blockCount[RBLOCKS]
    char* ws = (char*)d_ws;
    int*          starts     = (int*)ws;
    float*        blockSum   = (float*)(ws + 64 * 1024);
    unsigned int* blockCount = (unsigned int*)(ws + 72 * 1024);

    gather_starts<<<(SERIES + 255) / 256, 256, 0, stream>>>(indexes, rvsi, starts);

    masked_sq_reduce<<<RBLOCKS, RTHREADS, 0, stream>>>(
        (const float4*)predictions, (const float4*)actuals,
        (const int4*)starts, blockSum, blockCount);

    finalize<<<1, 256, 0, stream>>>(blockSum, blockCount, out);
}